// Round 2
// baseline (168.742 us; speedup 1.0000x reference)
//
#include <hip/hip_runtime.h>
#include <hip/hip_bf16.h>
#include <stdint.h>
#include <stddef.h>

typedef __bf16 bf16;
typedef __attribute__((ext_vector_type(4))) __bf16 bf16x4;
typedef __attribute__((ext_vector_type(8))) __bf16 bf16x8;
typedef __attribute__((ext_vector_type(4))) float f32x4;

#define BATCH 4096
#define DIM 1024
#define ODIM 1024
#define K3 3072   // 3 * DIM (x^3 | x^2 | x)

// workspace layout (bytes)
#define WS_P      0          // bf16 [4096][3072] = 25165824
#define WS_CB     25165824   // bf16 [1024][3072] = 6291456
#define WS_BIAS   31457280   // f32  [1024]
#define WS_PMIN   31461376   // f32  [256][1024] = 1048576
#define WS_PMAX   32509952   // f32  [256][1024]
#define WS_MINV   33558528   // f32  [1024]
#define WS_SCALE  33562624   // f32  [1024]

#define ASYNC16(g, l)                                                          \
  __builtin_amdgcn_global_load_lds(                                            \
      (__attribute__((address_space(1))) void*)(g),                            \
      (__attribute__((address_space(3))) void*)(l), 16, 0, 0)

// s_waitcnt imm: vmcnt[3:0]=bits3:0, expcnt=bits6:4, lgkmcnt=bits11:8, vmcnt[5:4]=bits15:14
#define WAIT_VM(n) __builtin_amdgcn_s_waitcnt(0x0F00 | 0x0070 | ((n)&15) | ((((n)>>4)&3)<<14))
#define BARRIER()                     \
  do {                                \
    asm volatile("" ::: "memory");    \
    __builtin_amdgcn_s_barrier();     \
    asm volatile("" ::: "memory");    \
  } while (0)

// ---- kernel 1: per-chunk column min/max (256 chunks of 16 rows, f32x4 rows) ----
__global__ void k_minmax_part(const float* __restrict__ x,
                              float* __restrict__ pmin,
                              float* __restrict__ pmax) {
  const int t = threadIdx.x;       // 256 threads: cols 4t..4t+3
  const int ch = blockIdx.x;       // 256 chunks of 16 rows
  const float* p = x + (size_t)ch * 16 * DIM + (t << 2);
  f32x4 mn = {1e30f, 1e30f, 1e30f, 1e30f};
  f32x4 mx = {-1e30f, -1e30f, -1e30f, -1e30f};
#pragma unroll
  for (int r = 0; r < 16; ++r) {
    f32x4 v = *(const f32x4*)(p + (size_t)r * DIM);
#pragma unroll
    for (int j = 0; j < 4; ++j) {
      mn[j] = fminf(mn[j], v[j]);
      mx[j] = fmaxf(mx[j], v[j]);
    }
  }
  *(f32x4*)(pmin + ch * DIM + (t << 2)) = mn;
  *(f32x4*)(pmax + ch * DIM + (t << 2)) = mx;
}

// ---- kernel 2: final reduce + scale ----
__global__ void k_minmax_final(const float* __restrict__ pmin,
                               const float* __restrict__ pmax,
                               float* __restrict__ minv,
                               float* __restrict__ scale) {
  int col = blockIdx.x * 256 + threadIdx.x;
  float mn = 1e30f, mx = -1e30f;
#pragma unroll 8
  for (int ch = 0; ch < 256; ++ch) {
    mn = fminf(mn, pmin[ch * DIM + col]);
    mx = fmaxf(mx, pmax[ch * DIM + col]);
  }
  minv[col] = mn;
  scale[col] = 1.0f / (mx - mn);
}

// ---- kernel 3 (fused): powers (blocks 0..2047, 2 rows/block, bf16x8 stores)
//                        + coeff reduce (blocks 2048..3071)
__global__ void k_prep(const float* __restrict__ x,
                       const float* __restrict__ minv,
                       const float* __restrict__ scale,
                       bf16* __restrict__ P,
                       const float* __restrict__ sp,
                       bf16* __restrict__ CB,
                       float* __restrict__ bias) {
  __shared__ float red[4];
  const int t = threadIdx.x;
  if (blockIdx.x < (BATCH / 2)) {
    const int b = blockIdx.x * 2 + (t >> 7);   // 2 rows per block
    const int d = (t & 127) << 3;              // 8 cols per thread
    f32x4 xv0 = *(const f32x4*)(x + (size_t)b * DIM + d);
    f32x4 xv1 = *(const f32x4*)(x + (size_t)b * DIM + d + 4);
    f32x4 mn0 = *(const f32x4*)(minv + d);
    f32x4 mn1 = *(const f32x4*)(minv + d + 4);
    f32x4 sc0 = *(const f32x4*)(scale + d);
    f32x4 sc1 = *(const f32x4*)(scale + d + 4);
    bf16x8 o3, o2, o1;
#pragma unroll
    for (int j = 0; j < 4; ++j) {
      float xn = (xv0[j] - mn0[j]) * sc0[j];
      float x2 = xn * xn;
      float x3 = x2 * xn;
      o3[j] = (bf16)x3;
      o2[j] = (bf16)x2;
      o1[j] = (bf16)xn;
      float yn = (xv1[j] - mn1[j]) * sc1[j];
      float y2 = yn * yn;
      float y3 = y2 * yn;
      o3[j + 4] = (bf16)y3;
      o2[j + 4] = (bf16)y2;
      o1[j + 4] = (bf16)yn;
    }
    size_t base = (size_t)b * K3 + d;
    *(bf16x8*)(P + base) = o3;
    *(bf16x8*)(P + base + 1024) = o2;
    *(bf16x8*)(P + base + 2048) = o1;
  } else {
    const int o = blockIdx.x - (BATCH / 2);
    const int d = t << 2;
    f32x4 s[4];
#pragma unroll
    for (int dd = 0; dd < 4; ++dd) {
      const float* p = sp + ((size_t)o * DIM + d + dd) * 16;  // [s=4][4]
      f32x4 acc = *(const f32x4*)(p);
      acc += *(const f32x4*)(p + 4);
      acc += *(const f32x4*)(p + 8);
      acc += *(const f32x4*)(p + 12);
      s[dd] = acc;
    }
    size_t cb = (size_t)o * K3 + d;
    bf16x4 c0 = {(bf16)s[0][0], (bf16)s[1][0], (bf16)s[2][0], (bf16)s[3][0]};
    bf16x4 c1 = {(bf16)s[0][1], (bf16)s[1][1], (bf16)s[2][1], (bf16)s[3][1]};
    bf16x4 c2 = {(bf16)s[0][2], (bf16)s[1][2], (bf16)s[2][2], (bf16)s[3][2]};
    *(bf16x4*)(CB + cb) = c0;
    *(bf16x4*)(CB + cb + 1024) = c1;
    *(bf16x4*)(CB + cb + 2048) = c2;
    float v = s[0][3] + s[1][3] + s[2][3] + s[3][3];
#pragma unroll
    for (int off = 32; off > 0; off >>= 1) v += __shfl_down(v, off, 64);
    int lane = t & 63, w = t >> 6;
    if (lane == 0) red[w] = v;
    __syncthreads();
    if (t == 0) bias[o] = red[0] + red[1] + red[2] + red[3];
  }
}

// ---- kernel 4: GEMM out[b][o] = P[b][:] . CB[o][:] + bias[o] ----
// 128x128 tile, BK=64, 4 waves each 64x64 (4x4 frags of 16x16x32).
// DEPTH-3 pipeline (4 LDS bufs, counted vmcnt(24)).
// XCD-CHUNK SWIZZLE: flat grid of 256 blocks; XCD = bid%8 (round-robin
// dispatch). bid = idx*8 + chunk, chunk = 2D region (Mgroup 0..3, Ngroup 0..1)
// of 8Mx4N tiles. Per-XCD working set: B = 4 N-panels = 3.1 MB (fits 4 MB L2),
// A streamed with 4-way reuse. LLC staging traffic 393 MB -> ~75 MB.
#define BM 128
#define BN 128
#define BKE 64   // K elems per iter; row = 128 B = 8 x 16B units
#define NIT (K3 / BKE)  // 48
#define NBUF 4
__global__ __launch_bounds__(256, 1) void k_gemm(const bf16* __restrict__ P,
                                                 const bf16* __restrict__ CBm,
                                                 const float* __restrict__ bias,
                                                 float* __restrict__ out) {
  __shared__ bf16 ldsm[NBUF][2][BM * BKE];  // 4 x 32 KB = 128 KB

  const int tid = threadIdx.x;
  const int wave = tid >> 6;
  const int lane = tid & 63;

  // XCD-chunk decode: bijective map flat bid -> (mt, nt) in 32x8 tile grid
  const int f = blockIdx.x;
  const int chunk = f & 7;       // lands on XCD (f % 8)
  const int idx = f >> 3;        // 0..31 within chunk
  const int mt = ((chunk >> 1) << 3) + (idx >> 2);  // Mgroup*8 + 0..7
  const int nt = ((chunk & 1) << 2) + (idx & 3);    // Ngroup*4 + 0..3
  const int bm = mt * BM;
  const int bn = nt * BN;

  const int wr = (wave >> 1) * 64;  // wave row origin (M)
  const int wc = (wave & 1) * 64;   // wave col origin (N)

  const size_t rowbytes = (size_t)K3 * 2;  // 6144

  // staging precompute: issue i covers LDS bytes [i*4096, i*4096+4096);
  // LDS slot (row, q) holds global 16B unit (row, q^(row&7)).
  const char* gAp[4];
  const char* gBp[4];
  int ldso[4];
#pragma unroll
  for (int i = 0; i < 4; ++i) {
    int off = i * 4096 + tid * 16;
    int row = off >> 7;          // 128B rows
    int q = (off >> 4) & 7;
    int gb = (q ^ (row & 7)) * 16;
    gAp[i] = (const char*)P + (size_t)(bm + row) * rowbytes + gb;
    gBp[i] = (const char*)CBm + (size_t)(bn + row) * rowbytes + gb;
    ldso[i] = i * 4096 + wave * 1024;  // wave-uniform base; HW adds lane*16
  }

  f32x4 acc[4][4] = {};

  const int mrow = lane & 15;
  const int kq = lane >> 4;  // 16B-unit index within a 32-elem k-window

#define STAGE(buf, kt)                                                        \
  do {                                                                        \
    const size_t kb_ = (size_t)(kt) * (BKE * 2);                              \
    char* lA_ = (char*)&ldsm[buf][0][0];                                      \
    char* lB_ = (char*)&ldsm[buf][1][0];                                      \
    _Pragma("unroll") for (int i_ = 0; i_ < 4; ++i_)                          \
        ASYNC16(gAp[i_] + kb_, lA_ + ldso[i_]);                               \
    _Pragma("unroll") for (int i_ = 0; i_ < 4; ++i_)                          \
        ASYNC16(gBp[i_] + kb_, lB_ + ldso[i_]);                               \
  } while (0)

#define COMPUTE(buf)                                                          \
  do {                                                                        \
    const bf16* sA_ = &ldsm[buf][0][0];                                       \
    const bf16* sB_ = &ldsm[buf][1][0];                                       \
    _Pragma("unroll") for (int ks = 0; ks < 2; ++ks) {                        \
      bf16x8 af[4], bg[4];                                                    \
      _Pragma("unroll") for (int i = 0; i < 4; ++i) {                         \
        int row = wr + i * 16 + mrow;                                         \
        int sq = (ks * 4 + kq) ^ (row & 7);                                   \
        af[i] = *(const bf16x8*)&sA_[row * BKE + sq * 8];                     \
      }                                                                       \
      _Pragma("unroll") for (int j = 0; j < 4; ++j) {                         \
        int row = wc + j * 16 + mrow;                                         \
        int sq = (ks * 4 + kq) ^ (row & 7);                                   \
        bg[j] = *(const bf16x8*)&sB_[row * BKE + sq * 8];                     \
      }                                                                       \
      _Pragma("unroll") for (int i = 0; i < 4; ++i)                           \
          _Pragma("unroll") for (int j = 0; j < 4; ++j)                       \
              acc[i][j] = __builtin_amdgcn_mfma_f32_16x16x32_bf16(            \
                  af[i], bg[j], acc[i][j], 0, 0, 0);                          \
    }                                                                         \
  } while (0)

  // prologue: tiles 0,1,2 -> bufs 0,1,2 (24 issues in flight)
  STAGE(0, 0);
  STAGE(1, 1);
  STAGE(2, 2);
#pragma unroll 4
  for (int kt = 0; kt < NIT - 3; ++kt) {
    STAGE((kt + 3) & 3, kt + 3);  // prefetch 3 tiles ahead
    WAIT_VM(24);                  // drain ONLY tile kt's 8 issues
    BARRIER();
    COMPUTE(kt & 3);
    BARRIER();                    // all waves done reading buf before overwrite
  }
  // peeled tail: tiles NIT-3, NIT-2, NIT-1 (bufs 1,2,3) — no more staging
  WAIT_VM(16);
  BARRIER();
  COMPUTE(1);
  BARRIER();
  WAIT_VM(8);
  BARRIER();
  COMPUTE(2);
  BARRIER();
  WAIT_VM(0);
  BARRIER();
  COMPUTE(3);

  // epilogue: C/D layout col=lane&15, row=(lane>>4)*4+reg
  const int ccol = lane & 15;
  const int crow = (lane >> 4) * 4;
#pragma unroll
  for (int j = 0; j < 4; ++j) {
    const int col = bn + wc + j * 16 + ccol;
    const float bv = bias[col];
#pragma unroll
    for (int i = 0; i < 4; ++i) {
      const int row0 = bm + wr + i * 16 + crow;
#pragma unroll
      for (int r = 0; r < 4; ++r)
        out[(size_t)(row0 + r) * ODIM + col] = acc[i][j][r] + bv;
    }
  }
#undef STAGE
#undef COMPUTE
}

extern "C" void kernel_launch(void* const* d_in, const int* in_sizes, int n_in,
                              void* d_out, int out_size, void* d_ws, size_t ws_size,
                              hipStream_t stream) {
  (void)in_sizes; (void)n_in; (void)out_size; (void)ws_size;
  const float* x = (const float*)d_in[0];
  const float* sp = (const float*)d_in[1];
  float* out = (float*)d_out;
  char* ws = (char*)d_ws;

  bf16* Pm = (bf16*)(ws + WS_P);
  bf16* CBm = (bf16*)(ws + WS_CB);
  float* bias = (float*)(ws + WS_BIAS);
  float* pmin = (float*)(ws + WS_PMIN);
  float* pmax = (float*)(ws + WS_PMAX);
  float* minv = (float*)(ws + WS_MINV);
  float* scale = (float*)(ws + WS_SCALE);

  k_minmax_part<<<256, 256, 0, stream>>>(x, pmin, pmax);
  k_minmax_final<<<4, 256, 0, stream>>>(pmin, pmax, minv, scale);
  k_prep<<<(BATCH / 2) + ODIM, 256, 0, stream>>>(x, minv, scale, Pm, sp, CBm, bias);
  k_gemm<<<256, 256, 0, stream>>>(Pm, CBm, bias, out);
}

// Round 3
// 155.560 us; speedup vs baseline: 1.0847x; 1.0847x over previous
//
#include <hip/hip_runtime.h>
#include <hip/hip_bf16.h>
#include <stdint.h>
#include <stddef.h>

typedef __bf16 bf16;
typedef __attribute__((ext_vector_type(4))) __bf16 bf16x4;
typedef __attribute__((ext_vector_type(8))) __bf16 bf16x8;
typedef __attribute__((ext_vector_type(4))) float f32x4;

#define BATCH 4096
#define DIM 1024
#define ODIM 1024
#define K3 3072   // 3 * DIM (x^3 | x^2 | x)

// workspace layout (bytes)
#define WS_P      0          // bf16 [4096][3072] = 25165824
#define WS_CB     25165824   // bf16 [1024][3072] = 6291456
#define WS_BIAS   31457280   // f32  [1024]
#define WS_PMIN   31461376   // f32  [256][1024] = 1048576
#define WS_PMAX   32509952   // f32  [256][1024]
#define WS_MINV   33558528   // f32  [1024]
#define WS_SCALE  33562624   // f32  [1024]

#define ASYNC16(g, l)                                                          \
  __builtin_amdgcn_global_load_lds(                                            \
      (__attribute__((address_space(1))) void*)(g),                            \
      (__attribute__((address_space(3))) void*)(l), 16, 0, 0)

// s_waitcnt imm: vmcnt[3:0]=bits3:0, expcnt=bits6:4, lgkmcnt=bits11:8, vmcnt[5:4]=bits15:14
#define WAIT_VM(n) __builtin_amdgcn_s_waitcnt(0x0F00 | 0x0070 | ((n)&15) | ((((n)>>4)&3)<<14))
#define BARRIER()                     \
  do {                                \
    asm volatile("" ::: "memory");    \
    __builtin_amdgcn_s_barrier();     \
    asm volatile("" ::: "memory");    \
  } while (0)

// ---- kernel 1 (FUSED): blocks 0..255  = per-chunk column min/max of x
//                        blocks 256..1279 = spline coeff reduce (independent)
// The two cold HBM streams (x: 16.8 MB, sp: 67 MB) now run CONCURRENTLY
// across all CUs instead of in two serialized kernels.
__global__ void k_stream(const float* __restrict__ x,
                         float* __restrict__ pmin,
                         float* __restrict__ pmax,
                         const float* __restrict__ sp,
                         bf16* __restrict__ CB,
                         float* __restrict__ bias) {
  __shared__ float red[4];
  const int t = threadIdx.x;
  if (blockIdx.x < 256) {
    // min/max over 16 rows per chunk
    const int ch = blockIdx.x;
    const float* p = x + (size_t)ch * 16 * DIM + (t << 2);
    f32x4 mn = {1e30f, 1e30f, 1e30f, 1e30f};
    f32x4 mx = {-1e30f, -1e30f, -1e30f, -1e30f};
#pragma unroll
    for (int r = 0; r < 16; ++r) {
      f32x4 v = *(const f32x4*)(p + (size_t)r * DIM);
#pragma unroll
      for (int j = 0; j < 4; ++j) {
        mn[j] = fminf(mn[j], v[j]);
        mx[j] = fmaxf(mx[j], v[j]);
      }
    }
    *(f32x4*)(pmin + ch * DIM + (t << 2)) = mn;
    *(f32x4*)(pmax + ch * DIM + (t << 2)) = mx;
  } else {
    // coeff reduce: c[o][d][:] = sum_s sp[o][d][s][:]
    const int o = blockIdx.x - 256;
    const int d = t << 2;
    f32x4 s[4];
#pragma unroll
    for (int dd = 0; dd < 4; ++dd) {
      const float* p = sp + ((size_t)o * DIM + d + dd) * 16;  // [s=4][4]
      f32x4 acc = *(const f32x4*)(p);
      acc += *(const f32x4*)(p + 4);
      acc += *(const f32x4*)(p + 8);
      acc += *(const f32x4*)(p + 12);
      s[dd] = acc;
    }
    size_t cb = (size_t)o * K3 + d;
    bf16x4 c0 = {(bf16)s[0][0], (bf16)s[1][0], (bf16)s[2][0], (bf16)s[3][0]};
    bf16x4 c1 = {(bf16)s[0][1], (bf16)s[1][1], (bf16)s[2][1], (bf16)s[3][1]};
    bf16x4 c2 = {(bf16)s[0][2], (bf16)s[1][2], (bf16)s[2][2], (bf16)s[3][2]};
    *(bf16x4*)(CB + cb) = c0;
    *(bf16x4*)(CB + cb + 1024) = c1;
    *(bf16x4*)(CB + cb + 2048) = c2;
    float v = s[0][3] + s[1][3] + s[2][3] + s[3][3];
#pragma unroll
    for (int off = 32; off > 0; off >>= 1) v += __shfl_down(v, off, 64);
    int lane = t & 63, w = t >> 6;
    if (lane == 0) red[w] = v;
    __syncthreads();
    if (t == 0) bias[o] = red[0] + red[1] + red[2] + red[3];
  }
}

// ---- kernel 2: final reduce + scale (16 blocks x 4 waves, coalesced) ----
__global__ void k_minmax_final(const float* __restrict__ pmin,
                               const float* __restrict__ pmax,
                               float* __restrict__ minv,
                               float* __restrict__ scale) {
  __shared__ float smn[4][64], smx[4][64];
  const int t = threadIdx.x;
  const int lane = t & 63;
  const int w = t >> 6;
  const int col = blockIdx.x * 64 + lane;
  float mn = 1e30f, mx = -1e30f;
#pragma unroll 8
  for (int ch = w; ch < 256; ch += 4) {
    mn = fminf(mn, pmin[ch * DIM + col]);
    mx = fmaxf(mx, pmax[ch * DIM + col]);
  }
  smn[w][lane] = mn;
  smx[w][lane] = mx;
  __syncthreads();
  if (w == 0) {
    mn = fminf(fminf(smn[0][lane], smn[1][lane]), fminf(smn[2][lane], smn[3][lane]));
    mx = fmaxf(fmaxf(smx[0][lane], smx[1][lane]), fmaxf(smx[2][lane], smx[3][lane]));
    minv[col] = mn;
    scale[col] = 1.0f / (mx - mn);
  }
}

// ---- kernel 3: powers only (2048 blocks, 2 rows/block, bf16x8 stores) ----
__global__ void k_powers(const float* __restrict__ x,
                         const float* __restrict__ minv,
                         const float* __restrict__ scale,
                         bf16* __restrict__ P) {
  const int t = threadIdx.x;
  const int b = blockIdx.x * 2 + (t >> 7);   // 2 rows per block
  const int d = (t & 127) << 3;              // 8 cols per thread
  f32x4 xv0 = *(const f32x4*)(x + (size_t)b * DIM + d);
  f32x4 xv1 = *(const f32x4*)(x + (size_t)b * DIM + d + 4);
  f32x4 mn0 = *(const f32x4*)(minv + d);
  f32x4 mn1 = *(const f32x4*)(minv + d + 4);
  f32x4 sc0 = *(const f32x4*)(scale + d);
  f32x4 sc1 = *(const f32x4*)(scale + d + 4);
  bf16x8 o3, o2, o1;
#pragma unroll
  for (int j = 0; j < 4; ++j) {
    float xn = (xv0[j] - mn0[j]) * sc0[j];
    float x2 = xn * xn;
    float x3 = x2 * xn;
    o3[j] = (bf16)x3;
    o2[j] = (bf16)x2;
    o1[j] = (bf16)xn;
    float yn = (xv1[j] - mn1[j]) * sc1[j];
    float y2 = yn * yn;
    float y3 = y2 * yn;
    o3[j + 4] = (bf16)y3;
    o2[j + 4] = (bf16)y2;
    o1[j + 4] = (bf16)yn;
  }
  size_t base = (size_t)b * K3 + d;
  *(bf16x8*)(P + base) = o3;
  *(bf16x8*)(P + base + 1024) = o2;
  *(bf16x8*)(P + base + 2048) = o1;
}

// ---- kernel 4: GEMM out[b][o] = P[b][:] . CB[o][:] + bias[o] ----
// 128x128 tile, BK=64, 4 waves each 64x64 (4x4 frags of 16x16x32).
// DEPTH-3 pipeline (4 LDS bufs, counted vmcnt(24)).
// XCD-CHUNK SWIZZLE: bid = idx*8 + chunk; chunk = 2D region of 8Mx4N tiles.
#define BM 128
#define BN 128
#define BKE 64   // K elems per iter; row = 128 B = 8 x 16B units
#define NIT (K3 / BKE)  // 48
#define NBUF 4
__global__ __launch_bounds__(256, 1) void k_gemm(const bf16* __restrict__ P,
                                                 const bf16* __restrict__ CBm,
                                                 const float* __restrict__ bias,
                                                 float* __restrict__ out) {
  __shared__ bf16 ldsm[NBUF][2][BM * BKE];  // 4 x 32 KB = 128 KB

  const int tid = threadIdx.x;
  const int wave = tid >> 6;
  const int lane = tid & 63;

  // XCD-chunk decode: bijective map flat bid -> (mt, nt) in 32x8 tile grid
  const int f = blockIdx.x;
  const int chunk = f & 7;       // lands on XCD (f % 8)
  const int idx = f >> 3;        // 0..31 within chunk
  const int mt = ((chunk >> 1) << 3) + (idx >> 2);  // Mgroup*8 + 0..7
  const int nt = ((chunk & 1) << 2) + (idx & 3);    // Ngroup*4 + 0..3
  const int bm = mt * BM;
  const int bn = nt * BN;

  const int wr = (wave >> 1) * 64;  // wave row origin (M)
  const int wc = (wave & 1) * 64;   // wave col origin (N)

  const size_t rowbytes = (size_t)K3 * 2;  // 6144

  // staging precompute: issue i covers LDS bytes [i*4096, i*4096+4096);
  // LDS slot (row, q) holds global 16B unit (row, q^(row&7)).
  const char* gAp[4];
  const char* gBp[4];
  int ldso[4];
#pragma unroll
  for (int i = 0; i < 4; ++i) {
    int off = i * 4096 + tid * 16;
    int row = off >> 7;          // 128B rows
    int q = (off >> 4) & 7;
    int gb = (q ^ (row & 7)) * 16;
    gAp[i] = (const char*)P + (size_t)(bm + row) * rowbytes + gb;
    gBp[i] = (const char*)CBm + (size_t)(bn + row) * rowbytes + gb;
    ldso[i] = i * 4096 + wave * 1024;  // wave-uniform base; HW adds lane*16
  }

  f32x4 acc[4][4] = {};

  const int mrow = lane & 15;
  const int kq = lane >> 4;  // 16B-unit index within a 32-elem k-window

#define STAGE(buf, kt)                                                        \
  do {                                                                        \
    const size_t kb_ = (size_t)(kt) * (BKE * 2);                              \
    char* lA_ = (char*)&ldsm[buf][0][0];                                      \
    char* lB_ = (char*)&ldsm[buf][1][0];                                      \
    _Pragma("unroll") for (int i_ = 0; i_ < 4; ++i_)                          \
        ASYNC16(gAp[i_] + kb_, lA_ + ldso[i_]);                               \
    _Pragma("unroll") for (int i_ = 0; i_ < 4; ++i_)                          \
        ASYNC16(gBp[i_] + kb_, lB_ + ldso[i_]);                               \
  } while (0)

#define COMPUTE(buf)                                                          \
  do {                                                                        \
    const bf16* sA_ = &ldsm[buf][0][0];                                       \
    const bf16* sB_ = &ldsm[buf][1][0];                                       \
    _Pragma("unroll") for (int ks = 0; ks < 2; ++ks) {                        \
      bf16x8 af[4], bg[4];                                                    \
      _Pragma("unroll") for (int i = 0; i < 4; ++i) {                         \
        int row = wr + i * 16 + mrow;                                         \
        int sq = (ks * 4 + kq) ^ (row & 7);                                   \
        af[i] = *(const bf16x8*)&sA_[row * BKE + sq * 8];                     \
      }                                                                       \
      _Pragma("unroll") for (int j = 0; j < 4; ++j) {                         \
        int row = wc + j * 16 + mrow;                                         \
        int sq = (ks * 4 + kq) ^ (row & 7);                                   \
        bg[j] = *(const bf16x8*)&sB_[row * BKE + sq * 8];                     \
      }                                                                       \
      _Pragma("unroll") for (int i = 0; i < 4; ++i)                           \
          _Pragma("unroll") for (int j = 0; j < 4; ++j)                       \
              acc[i][j] = __builtin_amdgcn_mfma_f32_16x16x32_bf16(            \
                  af[i], bg[j], acc[i][j], 0, 0, 0);                          \
    }                                                                         \
  } while (0)

  // prologue: tiles 0,1,2 -> bufs 0,1,2 (24 issues in flight)
  STAGE(0, 0);
  STAGE(1, 1);
  STAGE(2, 2);
#pragma unroll 4
  for (int kt = 0; kt < NIT - 3; ++kt) {
    STAGE((kt + 3) & 3, kt + 3);  // prefetch 3 tiles ahead
    WAIT_VM(24);                  // drain ONLY tile kt's 8 issues
    BARRIER();
    COMPUTE(kt & 3);
    BARRIER();                    // all waves done reading buf before overwrite
  }
  // peeled tail: tiles NIT-3, NIT-2, NIT-1 (bufs 1,2,3) — no more staging
  WAIT_VM(16);
  BARRIER();
  COMPUTE(1);
  BARRIER();
  WAIT_VM(8);
  BARRIER();
  COMPUTE(2);
  BARRIER();
  WAIT_VM(0);
  BARRIER();
  COMPUTE(3);

  // epilogue: C/D layout col=lane&15, row=(lane>>4)*4+reg
  const int ccol = lane & 15;
  const int crow = (lane >> 4) * 4;
#pragma unroll
  for (int j = 0; j < 4; ++j) {
    const int col = bn + wc + j * 16 + ccol;
    const float bv = bias[col];
#pragma unroll
    for (int i = 0; i < 4; ++i) {
      const int row0 = bm + wr + i * 16 + crow;
#pragma unroll
      for (int r = 0; r < 4; ++r)
        out[(size_t)(row0 + r) * ODIM + col] = acc[i][j][r] + bv;
    }
  }
#undef STAGE
#undef COMPUTE
}

extern "C" void kernel_launch(void* const* d_in, const int* in_sizes, int n_in,
                              void* d_out, int out_size, void* d_ws, size_t ws_size,
                              hipStream_t stream) {
  (void)in_sizes; (void)n_in; (void)out_size; (void)ws_size;
  const float* x = (const float*)d_in[0];
  const float* sp = (const float*)d_in[1];
  float* out = (float*)d_out;
  char* ws = (char*)d_ws;

  bf16* Pm = (bf16*)(ws + WS_P);
  bf16* CBm = (bf16*)(ws + WS_CB);
  float* bias = (float*)(ws + WS_BIAS);
  float* pmin = (float*)(ws + WS_PMIN);
  float* pmax = (float*)(ws + WS_PMAX);
  float* minv = (float*)(ws + WS_MINV);
  float* scale = (float*)(ws + WS_SCALE);

  // k_stream overlaps the two independent cold HBM reads (x and sp)
  k_stream<<<1280, 256, 0, stream>>>(x, pmin, pmax, sp, CBm, bias);
  k_minmax_final<<<16, 256, 0, stream>>>(pmin, pmax, minv, scale);
  k_powers<<<2048, 256, 0, stream>>>(x, minv, scale, Pm);
  k_gemm<<<256, 256, 0, stream>>>(Pm, CBm, bias, out);
}

// Round 4
// 152.432 us; speedup vs baseline: 1.1070x; 1.0205x over previous
//
#include <hip/hip_runtime.h>
#include <hip/hip_bf16.h>
#include <stdint.h>
#include <stddef.h>

typedef __bf16 bf16;
typedef __attribute__((ext_vector_type(4))) __bf16 bf16x4;
typedef __attribute__((ext_vector_type(8))) __bf16 bf16x8;
typedef __attribute__((ext_vector_type(4))) float f32x4;

#define BATCH 4096
#define DIM 1024
#define ODIM 1024
#define K3 3072   // 3 * DIM (x^3 | x^2 | x)

// workspace layout (bytes)
#define WS_P      0          // bf16 [4096][3072] = 25165824
#define WS_CB     25165824   // bf16 [1024][3072] = 6291456
#define WS_BIAS   31457280   // f32  [1024]
#define WS_PMIN   31461376   // f32  [256][1024] = 1048576
#define WS_PMAX   32509952   // f32  [256][1024]
#define WS_MINV   33558528   // f32  [1024]
#define WS_SCALE  33562624   // f32  [1024]

#define ASYNC16(g, l)                                                          \
  __builtin_amdgcn_global_load_lds(                                            \
      (__attribute__((address_space(1))) void*)(g),                            \
      (__attribute__((address_space(3))) void*)(l), 16, 0, 0)

// s_waitcnt imm: vmcnt[3:0]=bits3:0, expcnt=bits6:4, lgkmcnt=bits11:8, vmcnt[5:4]=bits15:14
#define WAIT_VM(n) __builtin_amdgcn_s_waitcnt(0x0F00 | 0x0070 | ((n)&15) | ((((n)>>4)&3)<<14))
#define BARRIER()                     \
  do {                                \
    asm volatile("" ::: "memory");    \
    __builtin_amdgcn_s_barrier();     \
    asm volatile("" ::: "memory");    \
  } while (0)

// ---- kernel 1 (FUSED): blocks 0..255  = per-chunk column min/max of x
//                        blocks 256..1279 = spline coeff reduce (independent)
// The two cold HBM streams (x: 16.8 MB, sp: 67 MB) run CONCURRENTLY.
__global__ void k_stream(const float* __restrict__ x,
                         float* __restrict__ pmin,
                         float* __restrict__ pmax,
                         const float* __restrict__ sp,
                         bf16* __restrict__ CB,
                         float* __restrict__ bias) {
  __shared__ float red[4];
  const int t = threadIdx.x;
  if (blockIdx.x < 256) {
    // min/max over 16 rows per chunk
    const int ch = blockIdx.x;
    const float* p = x + (size_t)ch * 16 * DIM + (t << 2);
    f32x4 mn = {1e30f, 1e30f, 1e30f, 1e30f};
    f32x4 mx = {-1e30f, -1e30f, -1e30f, -1e30f};
#pragma unroll
    for (int r = 0; r < 16; ++r) {
      f32x4 v = *(const f32x4*)(p + (size_t)r * DIM);
#pragma unroll
      for (int j = 0; j < 4; ++j) {
        mn[j] = fminf(mn[j], v[j]);
        mx[j] = fmaxf(mx[j], v[j]);
      }
    }
    *(f32x4*)(pmin + ch * DIM + (t << 2)) = mn;
    *(f32x4*)(pmax + ch * DIM + (t << 2)) = mx;
  } else {
    // coeff reduce: c[o][d][:] = sum_s sp[o][d][s][:]
    const int o = blockIdx.x - 256;
    const int d = t << 2;
    f32x4 s[4];
#pragma unroll
    for (int dd = 0; dd < 4; ++dd) {
      const float* p = sp + ((size_t)o * DIM + d + dd) * 16;  // [s=4][4]
      f32x4 acc = *(const f32x4*)(p);
      acc += *(const f32x4*)(p + 4);
      acc += *(const f32x4*)(p + 8);
      acc += *(const f32x4*)(p + 12);
      s[dd] = acc;
    }
    size_t cb = (size_t)o * K3 + d;
    bf16x4 c0 = {(bf16)s[0][0], (bf16)s[1][0], (bf16)s[2][0], (bf16)s[3][0]};
    bf16x4 c1 = {(bf16)s[0][1], (bf16)s[1][1], (bf16)s[2][1], (bf16)s[3][1]};
    bf16x4 c2 = {(bf16)s[0][2], (bf16)s[1][2], (bf16)s[2][2], (bf16)s[3][2]};
    *(bf16x4*)(CB + cb) = c0;
    *(bf16x4*)(CB + cb + 1024) = c1;
    *(bf16x4*)(CB + cb + 2048) = c2;
    float v = s[0][3] + s[1][3] + s[2][3] + s[3][3];
#pragma unroll
    for (int off = 32; off > 0; off >>= 1) v += __shfl_down(v, off, 64);
    int lane = t & 63, w = t >> 6;
    if (lane == 0) red[w] = v;
    __syncthreads();
    if (t == 0) bias[o] = red[0] + red[1] + red[2] + red[3];
  }
}

// ---- kernel 2: final reduce + scale (16 blocks x 4 waves, coalesced) ----
__global__ void k_minmax_final(const float* __restrict__ pmin,
                               const float* __restrict__ pmax,
                               float* __restrict__ minv,
                               float* __restrict__ scale) {
  __shared__ float smn[4][64], smx[4][64];
  const int t = threadIdx.x;
  const int lane = t & 63;
  const int w = t >> 6;
  const int col = blockIdx.x * 64 + lane;
  float mn = 1e30f, mx = -1e30f;
#pragma unroll 8
  for (int ch = w; ch < 256; ch += 4) {
    mn = fminf(mn, pmin[ch * DIM + col]);
    mx = fmaxf(mx, pmax[ch * DIM + col]);
  }
  smn[w][lane] = mn;
  smx[w][lane] = mx;
  __syncthreads();
  if (w == 0) {
    mn = fminf(fminf(smn[0][lane], smn[1][lane]), fminf(smn[2][lane], smn[3][lane]));
    mx = fmaxf(fmaxf(smx[0][lane], smx[1][lane]), fmaxf(smx[2][lane], smx[3][lane]));
    minv[col] = mn;
    scale[col] = 1.0f / (mx - mn);
  }
}

// ---- kernel 3: powers only (2048 blocks, 2 rows/block, bf16x8 stores) ----
__global__ void k_powers(const float* __restrict__ x,
                         const float* __restrict__ minv,
                         const float* __restrict__ scale,
                         bf16* __restrict__ P) {
  const int t = threadIdx.x;
  const int b = blockIdx.x * 2 + (t >> 7);   // 2 rows per block
  const int d = (t & 127) << 3;              // 8 cols per thread
  f32x4 xv0 = *(const f32x4*)(x + (size_t)b * DIM + d);
  f32x4 xv1 = *(const f32x4*)(x + (size_t)b * DIM + d + 4);
  f32x4 mn0 = *(const f32x4*)(minv + d);
  f32x4 mn1 = *(const f32x4*)(minv + d + 4);
  f32x4 sc0 = *(const f32x4*)(scale + d);
  f32x4 sc1 = *(const f32x4*)(scale + d + 4);
  bf16x8 o3, o2, o1;
#pragma unroll
  for (int j = 0; j < 4; ++j) {
    float xn = (xv0[j] - mn0[j]) * sc0[j];
    float x2 = xn * xn;
    float x3 = x2 * xn;
    o3[j] = (bf16)x3;
    o2[j] = (bf16)x2;
    o1[j] = (bf16)xn;
    float yn = (xv1[j] - mn1[j]) * sc1[j];
    float y2 = yn * yn;
    float y3 = y2 * yn;
    o3[j + 4] = (bf16)y3;
    o2[j + 4] = (bf16)y2;
    o1[j + 4] = (bf16)yn;
  }
  size_t base = (size_t)b * K3 + d;
  *(bf16x8*)(P + base) = o3;
  *(bf16x8*)(P + base + 1024) = o2;
  *(bf16x8*)(P + base + 2048) = o1;
}

// ---- kernel 4: GEMM out[b][o] = P[b][:] . CB[o][:] + bias[o] ----
// 128x128 tile, BK=64. *** 8 WAVES (512 threads) ***: wave owns a 64x32
// quadrant (acc 4x2). 2 waves/SIMD -> one wave's MFMAs hide the other's
// ds_read/addr cycles (the m114/m198 implicit-overlap mechanism; 4-wave
// version had 1 wave/SIMD = zero overlap, which is why latency/L2 levers
// were null). NBUF=3 (96 KB LDS), depth-2 prefetch, counted vmcnt.
// XCD-CHUNK SWIZZLE kept: bid = idx*8 + chunk; chunk = 8Mx4N region.
#define BM 128
#define BN 128
#define BKE 64   // K elems per iter; row = 128 B = 8 x 16B units
#define NIT (K3 / BKE)  // 48
#define NBUF 3
__global__ __launch_bounds__(512, 2) void k_gemm(const bf16* __restrict__ P,
                                                 const bf16* __restrict__ CBm,
                                                 const float* __restrict__ bias,
                                                 float* __restrict__ out) {
  __shared__ bf16 ldsm[NBUF][2][BM * BKE];  // 3 x 32 KB = 96 KB

  const int tid = threadIdx.x;
  const int wave = tid >> 6;
  const int lane = tid & 63;

  // XCD-chunk decode: bijective map flat bid -> (mt, nt) in 32x8 tile grid
  const int f = blockIdx.x;
  const int chunk = f & 7;       // lands on XCD (f % 8)
  const int idx = f >> 3;        // 0..31 within chunk
  const int mt = ((chunk >> 1) << 3) + (idx >> 2);  // Mgroup*8 + 0..7
  const int nt = ((chunk & 1) << 2) + (idx & 3);    // Ngroup*4 + 0..3
  const int bm = mt * BM;
  const int bn = nt * BN;

  const int wr = (wave >> 2) * 64;  // wave row origin (M): 0 or 64
  const int wc = (wave & 3) * 32;   // wave col origin (N): 0..96

  const size_t rowbytes = (size_t)K3 * 2;  // 6144

  // staging precompute: 512 threads; issue i covers LDS bytes
  // [i*8192, i*8192+8192). LDS slot (row, q) holds global unit (row, q^(row&7)).
  const char* gAp[2];
  const char* gBp[2];
  int ldso[2];
#pragma unroll
  for (int i = 0; i < 2; ++i) {
    int off = i * 8192 + tid * 16;
    int row = off >> 7;          // 128B rows
    int q = (off >> 4) & 7;
    int gb = (q ^ (row & 7)) * 16;
    gAp[i] = (const char*)P + (size_t)(bm + row) * rowbytes + gb;
    gBp[i] = (const char*)CBm + (size_t)(bn + row) * rowbytes + gb;
    ldso[i] = i * 8192 + wave * 1024;  // wave-uniform base; HW adds lane*16
  }

  f32x4 acc[4][2] = {};

  const int mrow = lane & 15;
  const int kq = lane >> 4;  // 16B-unit index within a 32-elem k-window

#define STAGE(buf, kt)                                                        \
  do {                                                                        \
    const size_t kb_ = (size_t)(kt) * (BKE * 2);                              \
    char* lA_ = (char*)&ldsm[buf][0][0];                                      \
    char* lB_ = (char*)&ldsm[buf][1][0];                                      \
    _Pragma("unroll") for (int i_ = 0; i_ < 2; ++i_)                          \
        ASYNC16(gAp[i_] + kb_, lA_ + ldso[i_]);                               \
    _Pragma("unroll") for (int i_ = 0; i_ < 2; ++i_)                          \
        ASYNC16(gBp[i_] + kb_, lB_ + ldso[i_]);                               \
  } while (0)

#define COMPUTE(buf)                                                          \
  do {                                                                        \
    const bf16* sA_ = &ldsm[buf][0][0];                                       \
    const bf16* sB_ = &ldsm[buf][1][0];                                       \
    _Pragma("unroll") for (int ks = 0; ks < 2; ++ks) {                        \
      bf16x8 af[4], bg[2];                                                    \
      _Pragma("unroll") for (int i = 0; i < 4; ++i) {                         \
        int row = wr + i * 16 + mrow;                                         \
        int sq = (ks * 4 + kq) ^ (row & 7);                                   \
        af[i] = *(const bf16x8*)&sA_[row * BKE + sq * 8];                     \
      }                                                                       \
      _Pragma("unroll") for (int j = 0; j < 2; ++j) {                         \
        int row = wc + j * 16 + mrow;                                         \
        int sq = (ks * 4 + kq) ^ (row & 7);                                   \
        bg[j] = *(const bf16x8*)&sB_[row * BKE + sq * 8];                     \
      }                                                                       \
      _Pragma("unroll") for (int i = 0; i < 4; ++i)                           \
          _Pragma("unroll") for (int j = 0; j < 2; ++j)                       \
              acc[i][j] = __builtin_amdgcn_mfma_f32_16x16x32_bf16(            \
                  af[i], bg[j], acc[i][j], 0, 0, 0);                          \
    }                                                                         \
  } while (0)

  // prologue: tiles 0,1 -> bufs 0,1 (8 issues in flight)
  STAGE(0, 0);
  STAGE(1, 1);
#pragma unroll 3
  for (int kt = 0; kt < NIT - 2; ++kt) {
    STAGE((kt + 2) % NBUF, kt + 2);  // prefetch 2 tiles ahead
    WAIT_VM(8);                      // drain ONLY tile kt's 4 issues
    BARRIER();
    COMPUTE(kt % NBUF);
    BARRIER();                       // all waves done reading buf before overwrite
  }
  // peeled tail: tiles NIT-2, NIT-1 — no more staging
  WAIT_VM(4);
  BARRIER();
  COMPUTE((NIT - 2) % NBUF);
  BARRIER();
  WAIT_VM(0);
  BARRIER();
  COMPUTE((NIT - 1) % NBUF);

  // epilogue: C/D layout col=lane&15, row=(lane>>4)*4+reg
  const int ccol = lane & 15;
  const int crow = (lane >> 4) * 4;
#pragma unroll
  for (int j = 0; j < 2; ++j) {
    const int col = bn + wc + j * 16 + ccol;
    const float bv = bias[col];
#pragma unroll
    for (int i = 0; i < 4; ++i) {
      const int row0 = bm + wr + i * 16 + crow;
#pragma unroll
      for (int r = 0; r < 4; ++r)
        out[(size_t)(row0 + r) * ODIM + col] = acc[i][j][r] + bv;
    }
  }
#undef STAGE
#undef COMPUTE
}

extern "C" void kernel_launch(void* const* d_in, const int* in_sizes, int n_in,
                              void* d_out, int out_size, void* d_ws, size_t ws_size,
                              hipStream_t stream) {
  (void)in_sizes; (void)n_in; (void)out_size; (void)ws_size;
  const float* x = (const float*)d_in[0];
  const float* sp = (const float*)d_in[1];
  float* out = (float*)d_out;
  char* ws = (char*)d_ws;

  bf16* Pm = (bf16*)(ws + WS_P);
  bf16* CBm = (bf16*)(ws + WS_CB);
  float* bias = (float*)(ws + WS_BIAS);
  float* pmin = (float*)(ws + WS_PMIN);
  float* pmax = (float*)(ws + WS_PMAX);
  float* minv = (float*)(ws + WS_MINV);
  float* scale = (float*)(ws + WS_SCALE);

  // k_stream overlaps the two independent cold HBM reads (x and sp)
  k_stream<<<1280, 256, 0, stream>>>(x, pmin, pmax, sp, CBm, bias);
  k_minmax_final<<<16, 256, 0, stream>>>(pmin, pmax, minv, scale);
  k_powers<<<2048, 256, 0, stream>>>(x, minv, scale, Pm);
  k_gemm<<<256, 512, 0, stream>>>(Pm, CBm, bias, out);
}